// Round 8
// baseline (62.289 us; speedup 1.0000x reference)
//
#include <hip/hip_runtime.h>

#define DIMK 128
#define SLICE_TILES 4

typedef __bf16 bf16x8 __attribute__((ext_vector_type(8)));
typedef float  f32x4  __attribute__((ext_vector_type(4)));

// ---- helpers ---------------------------------------------------------------
__device__ inline unsigned short f32_to_bf16_rne(float f) {
    unsigned u = __float_as_uint(f);
    u += 0x7FFFu + ((u >> 16) & 1u);      // round-to-nearest-even
    return (unsigned short)(u >> 16);
}

// Fragment-pack layout for a 16-row tile:
//   ushort offset = tile*2048 + kk*512 + (kb*16 + col)*8 + j
// for element [tile*16+col][kk*32 + kb*8 + j]; per-lane (lane = kb*16+col)
// a fragment load is  base + kk*512 + lane*8  -> 16B contiguous per lane.

// ---- kernel 1: pack fp32 rows -> scaled bf16 fragment tiles + row norms ----
__global__ void pack_rows(const float* __restrict__ src,
                          unsigned short* __restrict__ dst,
                          float* __restrict__ norm2,
                          int n_valid, int n_rows_pad, float scale) {
    int wave = threadIdx.x >> 6, lane = threadIdx.x & 63;
    int row = blockIdx.x * 4 + wave;
    if (row >= n_rows_pad) return;
    int srow = min(row, n_valid - 1);
    int e = lane * 2;
    float2 v = *(const float2*)(src + (size_t)srow * DIMK + e);
    unsigned pk = (unsigned)f32_to_bf16_rne(scale * v.x) |
                  ((unsigned)f32_to_bf16_rne(scale * v.y) << 16);
    int tile = row >> 4, col = row & 15;
    int kk = e >> 5, kb = (e >> 3) & 3, j = e & 7;
    size_t off = (size_t)tile * 2048 + kk * 512 + (kb * 16 + col) * 8 + j;
    *(unsigned*)(dst + off) = pk;           // j even -> dword aligned
    float s = v.x * v.x + v.y * v.y;        // norms from UNscaled values
#pragma unroll
    for (int o = 1; o < 64; o <<= 1) s += __shfl_xor(s, o, 64);
    if (lane == 0) norm2[row] = s;
}

// ---- kernel 2: segment counts -> per-position (t2, w) packed float2 --------
__global__ void seg_weights(const int* __restrict__ ids,
                            const int* __restrict__ nseg_p,
                            const float* __restrict__ t2,
                            float2* __restrict__ tw, int n_pos) {
    __shared__ int   cnt[256];
    __shared__ float w[256];
    int nseg = nseg_p[0];
    if (nseg > 256) nseg = 256;
    int t = threadIdx.x;
    if (t < nseg) cnt[t] = 0;
    __syncthreads();
    for (int p = t; p < n_pos; p += blockDim.x) atomicAdd(&cnt[ids[p]], 1);
    __syncthreads();
    if (t < nseg) w[t] = 1.0f / ((float)nseg * (float)max(cnt[t], 1));
    __syncthreads();
    for (int p = t; p < n_pos; p += blockDim.x) {
        float2 e; e.x = t2[p]; e.y = w[ids[p]];
        tw[p] = e;
    }
}

// ---- kernel 3: fused cross-GEMM + sqrt + weighted reduce -------------------
// Grid FLIPPED: blockIdx.x = position slice (fast-varying -> consecutive
// blocks share one pred panel; target stays L2-resident), blockIdx.y = node
// panel (128 nodes). 4 waves/block, wave owns 32 nodes. Block stages its
// 4-tile slice (16 KB) once, syncs once, then runs barrier-free unrolled
// compute. tw in registers, prefetched 1 tile ahead. Target packed with
// scale -2 so squared distance = d + t2 + p2.
__global__ __launch_bounds__(256, 6)
void l2dist_main(const unsigned short* __restrict__ pb,   // packed bf16 pred
                 const float* __restrict__ p2,
                 const unsigned short* __restrict__ tb,   // packed bf16(-2*t)
                 const float2* __restrict__ tw,
                 float* __restrict__ out,
                 int n_nodes) {
    __shared__ __align__(16) unsigned short lbuf[SLICE_TILES][2048];  // 16 KB
    const int tid  = threadIdx.x;
    const int lane = tid & 63;
    const int wave = tid >> 6;
    const int col  = lane & 15;
    const int kb   = lane >> 4;
    const int n0   = blockIdx.y * 128 + wave * 32;

    // stage the slice first (longest latency) ...
    const int pbase = blockIdx.x * SLICE_TILES;
    const unsigned short* sgp = tb + (size_t)pbase * 2048 + wave * 512 + lane * 8;
    unsigned short* ldst = &lbuf[0][0] + wave * 512;
#pragma unroll
    for (int t = 0; t < SLICE_TILES; ++t) {
        __builtin_amdgcn_global_load_lds(
            (const __attribute__((address_space(1))) unsigned int*)(const void*)
                (sgp + (size_t)t * 2048),
            (__attribute__((address_space(3))) unsigned int*)(void*)
                (ldst + t * 2048),
            16, 0, 0);
    }

    // ... then B fragments (2 node groups) + norms, overlapping the stage.
    bf16x8 bfrag[2][4];
    float p2g[2];
    const unsigned short* bp = pb + ((size_t)(n0 >> 4)) * 2048 + (size_t)lane * 8;
#pragma unroll
    for (int g = 0; g < 2; ++g) {
#pragma unroll
        for (int kk = 0; kk < 4; ++kk)
            bfrag[g][kk] = *(const bf16x8*)(bp + g * 2048 + kk * 512);
        p2g[g] = p2[n0 + g * 16 + col];
    }

    // tw preload for tile 0 (registers)
    const float2* twp = tw + ((size_t)pbase << 4) + kb * 4;
    f32x4 cw0 = *(const f32x4*)(twp);
    f32x4 cw1 = *(const f32x4*)(twp + 2);

    __syncthreads();    // drains stage; LDS read-only afterwards

    float acc0 = 0.f, acc1 = 0.f;
#pragma unroll
    for (int t = 0; t < SLICE_TILES; ++t) {
        // prefetch next tile's tw while this tile computes
        f32x4 nw0 = cw0, nw1 = cw1;
        if (t + 1 < SLICE_TILES) {
            nw0 = *(const f32x4*)(twp + 16 * (t + 1));
            nw1 = *(const f32x4*)(twp + 16 * (t + 1) + 2);
        }

        const unsigned short* rb = &lbuf[t][lane * 8];
        bf16x8 a0 = *(const bf16x8*)(rb);
        bf16x8 a1 = *(const bf16x8*)(rb + 512);
        bf16x8 a2 = *(const bf16x8*)(rb + 1024);
        bf16x8 a3 = *(const bf16x8*)(rb + 1536);

        f32x4 d0 = {0.f, 0.f, 0.f, 0.f};
        f32x4 d1 = {0.f, 0.f, 0.f, 0.f};
        d0 = __builtin_amdgcn_mfma_f32_16x16x32_bf16(a0, bfrag[0][0], d0, 0, 0, 0);
        d1 = __builtin_amdgcn_mfma_f32_16x16x32_bf16(a0, bfrag[1][0], d1, 0, 0, 0);
        d0 = __builtin_amdgcn_mfma_f32_16x16x32_bf16(a1, bfrag[0][1], d0, 0, 0, 0);
        d1 = __builtin_amdgcn_mfma_f32_16x16x32_bf16(a1, bfrag[1][1], d1, 0, 0, 0);
        d0 = __builtin_amdgcn_mfma_f32_16x16x32_bf16(a2, bfrag[0][2], d0, 0, 0, 0);
        d1 = __builtin_amdgcn_mfma_f32_16x16x32_bf16(a2, bfrag[1][2], d1, 0, 0, 0);
        d0 = __builtin_amdgcn_mfma_f32_16x16x32_bf16(a3, bfrag[0][3], d0, 0, 0, 0);
        d1 = __builtin_amdgcn_mfma_f32_16x16x32_bf16(a3, bfrag[1][3], d1, 0, 0, 0);

        // lane's 4 accumulator rows: kb*4 + {0..3}; cw = {t2,w} pairs
        float t2v[4] = {cw0[0], cw0[2], cw1[0], cw1[2]};
        float wv[4]  = {cw0[1], cw0[3], cw1[1], cw1[3]};
#pragma unroll
        for (int j = 0; j < 4; ++j) {
            float s0 = d0[j] + (t2v[j] + p2g[0]);   // d = -2*cross
            float s1 = d1[j] + (t2v[j] + p2g[1]);
            acc0 = fmaf(wv[j], __builtin_amdgcn_sqrtf(fmaxf(s0, 0.f)), acc0);
            acc1 = fmaf(wv[j], __builtin_amdgcn_sqrtf(fmaxf(s1, 0.f)), acc1);
        }
        cw0 = nw0; cw1 = nw1;
    }

    // reduce over the 4 kb lane-groups -> per-node totals
    acc0 += __shfl_xor(acc0, 16, 64);
    acc0 += __shfl_xor(acc0, 32, 64);
    acc1 += __shfl_xor(acc1, 16, 64);
    acc1 += __shfl_xor(acc1, 32, 64);
    if (lane < 16) {
        int na = n0 + col;
        int nb = n0 + 16 + col;
        if (na < n_nodes) atomicAdd(out + na, acc0);
        if (nb < n_nodes) atomicAdd(out + nb, acc1);
    }
}

// ---- launcher --------------------------------------------------------------
extern "C" void kernel_launch(void* const* d_in, const int* in_sizes, int n_in,
                              void* d_out, int out_size, void* d_ws, size_t ws_size,
                              hipStream_t stream) {
    const float* pred  = (const float*)d_in[0];
    const float* tgt   = (const float*)d_in[1];
    const int*   ids   = (const int*)d_in[2];
    const int*   nsegp = (const int*)d_in[3];
    float* out = (float*)d_out;

    int n_nodes = in_sizes[0] / DIMK;
    int n_pos   = in_sizes[2];

    int gy = (n_nodes + 127) / 128;          // node panels (128 nodes each)
    int n_rows_pad = gy * 128;               // pad pred tiles to grid coverage

    char* ws = (char*)d_ws;
    size_t off_pb = 0;                                        // packed pred bf16
    size_t off_tb = off_pb + (size_t)n_rows_pad * DIMK * 2;   // packed -2*target
    size_t off_p2 = off_tb + (size_t)n_pos * DIMK * 2;        // pred norms
    size_t off_t2 = off_p2 + (size_t)n_rows_pad * 4;          // target norms
    size_t off_tw = off_t2 + (size_t)n_pos * 4;               // (t2, w) pairs
    unsigned short* pb = (unsigned short*)(ws + off_pb);
    unsigned short* tb = (unsigned short*)(ws + off_tb);
    float*          p2 = (float*)(ws + off_p2);
    float*          t2 = (float*)(ws + off_t2);
    float2*         tw = (float2*)(ws + off_tw);

    pack_rows<<<(n_rows_pad + 3) / 4, 256, 0, stream>>>(pred, pb, p2, n_nodes, n_rows_pad, 1.0f);
    pack_rows<<<(n_pos + 3) / 4, 256, 0, stream>>>(tgt, tb, t2, n_pos, n_pos, -2.0f);
    seg_weights<<<1, 1024, 0, stream>>>(ids, nsegp, t2, tw, n_pos);
    hipMemsetAsync(out, 0, (size_t)out_size * sizeof(float), stream);

    int gx = (n_pos >> 4) / SLICE_TILES;     // 32 position slices
    dim3 grid(gx, gy);                        // x fast-varying: slices share pred panel
    l2dist_main<<<grid, 256, 0, stream>>>(pb, p2, tb, tw, out, n_nodes);
}